// Round 19
// baseline (83.426 us; speedup 1.0000x reference)
//
#include <hip/hip_runtime.h>
#include <hip/hip_bf16.h>
#include <math.h>

#define NPIX 4096
#define CH 64
#define BATCH 4
#define NSPLIT 4

typedef __attribute__((ext_vector_type(8))) short short8;
typedef __attribute__((ext_vector_type(4))) float f32x4;
typedef __attribute__((ext_vector_type(4))) unsigned short us4;
typedef __attribute__((ext_vector_type(4))) unsigned int u32x4;

static __device__ __forceinline__ unsigned short f2bf(float f) {
  union { float f; unsigned u; } v; v.f = f;
  unsigned u = v.u;
  unsigned r = u + 0x7FFF + ((u >> 16) & 1);
  return (unsigned short)(r >> 16);
}
static __device__ __forceinline__ float bf2f(unsigned short u) {
  union { unsigned u; float f; } v; v.u = ((unsigned)u) << 16; return v.f;
}
static __device__ __forceinline__ unsigned cvtpk(float lo, float hi) {
  unsigned r;
  asm("v_cvt_pk_bf16_f32 %0, %1, %2" : "=v"(r) : "v"(lo), "v"(hi));
  return r;
}

// ---------------- K1: LayerNorm(C) + q-proj MFMA GEMM, fused ------------------
__global__ __launch_bounds__(256) void k_ln_q(
    const float* __restrict__ x, const float* __restrict__ lg, const float* __restrict__ lb,
    const float* __restrict__ qw, const float* __restrict__ qb,
    float* __restrict__ xn, unsigned short* __restrict__ Q)
{
  __shared__ float xT[64][64];                 // [c][px] f32
  __shared__ unsigned short xB[64][64];        // [px][c] bf16, chunk-swizzled
  int tid = threadIdx.x, px = tid & 63, g4 = tid >> 6;
  int idx0 = blockIdx.x * 64;
  int idx = idx0 + px;
  int b = idx >> 12, p = idx & 4095;
  const float* xb = x + (size_t)b * CH * NPIX + p;
  for (int j = 0; j < 16; ++j) { int c = 16 * g4 + j; xT[c][px] = xb[(size_t)c * NPIX]; }
  __syncthreads();
  float xv[64]; float s = 0.f;
#pragma unroll
  for (int c = 0; c < 64; ++c) { xv[c] = xT[c][px]; s += xv[c]; }
  float mu = s * (1.f / 64.f), vs = 0.f;
#pragma unroll
  for (int c = 0; c < 64; ++c) { float d = xv[c] - mu; vs += d * d; }
  float rs = rsqrtf(vs * (1.f / 64.f) + 1e-5f);
#pragma unroll
  for (int c = 0; c < 64; ++c) xv[c] = (xv[c] - mu) * rs * lg[c] + lb[c];

  float* xnb = xn + (size_t)b * CH * NPIX + p;
#define LNQ_WR(C0)                                                             \
  {                                                                            \
    unsigned short t[16];                                                      \
    _Pragma("unroll") for (int j = 0; j < 16; ++j) {                           \
      float v = xv[C0 + j];                                                    \
      xnb[(size_t)(C0 + j) * NPIX] = v;                                        \
      t[j] = f2bf(v);                                                          \
    }                                                                          \
    *(short8*)&xB[px][(((C0 / 8) + 0) ^ (px & 7)) * 8] = *(short8*)t;          \
    *(short8*)&xB[px][(((C0 / 8) + 1) ^ (px & 7)) * 8] = *(short8*)(t + 8);    \
  }
  if (g4 == 0) LNQ_WR(0)
  else if (g4 == 1) LNQ_WR(16)
  else if (g4 == 2) LNQ_WR(32)
  else LNQ_WR(48)
#undef LNQ_WR
  __syncthreads();

  int lane = tid & 63, l15 = lane & 15, gg = lane >> 4;
  short8 af[2];
#pragma unroll
  for (int kc = 0; kc < 2; ++kc) {
    const float* wp = qw + (size_t)(g4 * 16 + l15) * 64 + kc * 32 + 8 * gg;
    unsigned short t[8];
#pragma unroll
    for (int j = 0; j < 8; ++j) t[j] = f2bf(wp[j]);
    af[kc] = *(short8*)t;
  }
  float bv[4];
#pragma unroll
  for (int r = 0; r < 4; ++r) bv[r] = qb[g4 * 16 + 4 * gg + r];
#pragma unroll
  for (int ct = 0; ct < 4; ++ct) {
    f32x4 acc = {bv[0], bv[1], bv[2], bv[3]};
    int row = ct * 16 + l15;
    short8 bf0 = *(const short8*)&xB[row][((0 + gg) ^ (row & 7)) * 8];
    short8 bf1 = *(const short8*)&xB[row][((4 + gg) ^ (row & 7)) * 8];
    acc = __builtin_amdgcn_mfma_f32_16x16x32_bf16(af[0], bf0, acc, 0, 0, 0);
    acc = __builtin_amdgcn_mfma_f32_16x16x32_bf16(af[1], bf1, acc, 0, 0, 0);
    us4 v;
#pragma unroll
    for (int r = 0; r < 4; ++r) v[r] = f2bf(acc[r] * 0.125f);
    *(us4*)(Q + (size_t)(idx0 + row) * 64 + g4 * 16 + 4 * gg) = v;
  }
}

// ---------------- K2: depthwise 3x3 for k and v (channel-split) ---------------
__global__ __launch_bounds__(256) void k_dwkv(
    const float* __restrict__ xn,
    const float* __restrict__ kw, const float* __restrict__ kb,
    const float* __restrict__ vw, const float* __restrict__ vb,
    unsigned short* __restrict__ K, unsigned short* __restrict__ VT)
{
  int idx = blockIdx.x * 256 + threadIdx.x;
  int b = idx >> 12, p = idx & 4095;
  int h = p >> 6, w = p & 63;
  int c0 = blockIdx.y * 8;
  size_t base = (size_t)b * CH * NPIX;
  unsigned short kq[8];
#pragma unroll
  for (int j = 0; j < 8; ++j) {
    int c = c0 + j;
    const float* xc = xn + base + (size_t)c * NPIX;
    float ka = kb[c], va = vb[c];
#pragma unroll
    for (int dy = -1; dy <= 1; ++dy) {
#pragma unroll
      for (int dx = -1; dx <= 1; ++dx) {
        int hh = h + dy, ww = w + dx;
        float xvv = (hh >= 0 && hh < 64 && ww >= 0 && ww < 64) ? xc[hh * 64 + ww] : 0.f;
        int t = (dy + 1) * 3 + (dx + 1);
        ka += kw[c * 9 + t] * xvv;
        va += vw[c * 9 + t] * xvv;
      }
    }
    kq[j] = f2bf(ka);
    VT[((size_t)b * CH + c) * NPIX + p] = f2bf(va);
  }
  *(short8*)(K + (size_t)idx * 64 + c0) = *(short8*)(kq);
}

// ---------------- K3: hybrid attention, 32 q-rows/wave ------------------------
#define SW(r) ((((r) & 7) ^ (((r) >> 3) << 1)) & 7)
__global__ __launch_bounds__(256, 4) void k_attn(
    const unsigned short* __restrict__ Q, const unsigned short* __restrict__ K,
    const unsigned short* __restrict__ VT, unsigned short* __restrict__ OPb,
    float* __restrict__ LS)
{
  __shared__ unsigned short kls[2][64][64];
  __shared__ unsigned short vls[2][64][64];

  int tid = threadIdx.x;
  int wid = tid >> 6, lane = tid & 63;
  int l15 = lane & 15, g = lane >> 4;
  int b = blockIdx.y, split = blockIdx.z;
  int nbase = blockIdx.x * 128 + wid * 32;

  const unsigned short* Qb = Q + (size_t)b * NPIX * CH;
  const unsigned short* Kb = K + (size_t)b * NPIX * CH;
  const unsigned short* Vb = VT + (size_t)b * CH * NPIX;

  short8 qf0a = *(const short8*)(Qb + (size_t)(nbase + l15) * CH + 8 * g);
  short8 qf1a = *(const short8*)(Qb + (size_t)(nbase + l15) * CH + 32 + 8 * g);
  short8 qf0b = *(const short8*)(Qb + (size_t)(nbase + 16 + l15) * CH + 8 * g);
  short8 qf1b = *(const short8*)(Qb + (size_t)(nbase + 16 + l15) * CH + 32 + 8 * g);

  f32x4 acca[4], accb[4];
#pragma unroll
  for (int i = 0; i < 4; ++i) {
    acca[i] = (f32x4){0.f, 0.f, 0.f, 0.f};
    accb[i] = (f32x4){0.f, 0.f, 0.f, 0.f};
  }
  float lsa = 0.f, lsb = 0.f;

  int srow = tid >> 3, sch = tid & 7;
  int srow1 = srow + 32;
  int wa0 = srow * 64 + ((sch ^ SW(srow)) * 8);
  int wa1 = srow1 * 64 + ((sch ^ SW(srow1)) * 8);
  const unsigned short* ksrc0 = Kb + (size_t)(split * 1024 + srow) * CH + sch * 8;
  const unsigned short* ksrc1 = Kb + (size_t)(split * 1024 + srow1) * CH + sch * 8;
  const unsigned short* vsrc0 = Vb + (size_t)srow * NPIX + split * 1024 + sch * 8;
  const unsigned short* vsrc1 = Vb + (size_t)srow1 * NPIX + split * 1024 + sch * 8;

  int kperm = 8 * (l15 >> 2) + (l15 & 3);

  short8 kg0, kg1, vg0, vg1;
  kg0 = *(const short8*)(ksrc0);
  kg1 = *(const short8*)(ksrc1);
  vg0 = *(const short8*)(vsrc0);
  vg1 = *(const short8*)(vsrc1);
  *(short8*)(&kls[0][0][0] + wa0) = kg0;
  *(short8*)(&kls[0][0][0] + wa1) = kg1;
  *(short8*)(&vls[0][0][0] + wa0) = vg0;
  *(short8*)(&vls[0][0][0] + wa1) = vg1;
  __syncthreads();

  for (int t = 0; t < 16; ++t) {
    if (t < 15) {
      int ko = (t + 1) * 64;
      kg0 = *(const short8*)(ksrc0 + (size_t)ko * CH);
      kg1 = *(const short8*)(ksrc1 + (size_t)ko * CH);
      vg0 = *(const short8*)(vsrc0 + ko);
      vg1 = *(const short8*)(vsrc1 + ko);
    }

    const unsigned short* kb = &kls[t & 1][0][0];
    const unsigned short* vb = &vls[t & 1][0][0];

#pragma unroll
    for (int s = 0; s < 2; ++s) {
      int r0 = s * 32 + kperm;
      int r1 = s * 32 + 4 + kperm;
      short8 kf00 = *(const short8*)(kb + r0 * 64 + (((0 + g) ^ SW(r0)) * 8));
      short8 kf01 = *(const short8*)(kb + r0 * 64 + (((4 + g) ^ SW(r0)) * 8));
      short8 kf10 = *(const short8*)(kb + r1 * 64 + (((0 + g) ^ SW(r1)) * 8));
      short8 kf11 = *(const short8*)(kb + r1 * 64 + (((4 + g) ^ SW(r1)) * 8));
      f32x4 sa0 = {0.f,0.f,0.f,0.f}, sa1 = {0.f,0.f,0.f,0.f};
      f32x4 sb0 = {0.f,0.f,0.f,0.f}, sb1 = {0.f,0.f,0.f,0.f};
      sa0 = __builtin_amdgcn_mfma_f32_16x16x32_bf16(kf00, qf0a, sa0, 0, 0, 0);
      sa0 = __builtin_amdgcn_mfma_f32_16x16x32_bf16(kf01, qf1a, sa0, 0, 0, 0);
      sa1 = __builtin_amdgcn_mfma_f32_16x16x32_bf16(kf10, qf0a, sa1, 0, 0, 0);
      sa1 = __builtin_amdgcn_mfma_f32_16x16x32_bf16(kf11, qf1a, sa1, 0, 0, 0);
      sb0 = __builtin_amdgcn_mfma_f32_16x16x32_bf16(kf00, qf0b, sb0, 0, 0, 0);
      sb0 = __builtin_amdgcn_mfma_f32_16x16x32_bf16(kf01, qf1b, sb0, 0, 0, 0);
      sb1 = __builtin_amdgcn_mfma_f32_16x16x32_bf16(kf10, qf0b, sb1, 0, 0, 0);
      sb1 = __builtin_amdgcn_mfma_f32_16x16x32_bf16(kf11, qf1b, sb1, 0, 0, 0);

      float a0 = __expf(sa0[0]), a1 = __expf(sa0[1]), a2 = __expf(sa0[2]), a3 = __expf(sa0[3]);
      float a4 = __expf(sa1[0]), a5 = __expf(sa1[1]), a6 = __expf(sa1[2]), a7 = __expf(sa1[3]);
      lsa += (a0 + a1) + (a2 + a3) + (a4 + a5) + (a6 + a7);
      u32x4 pka;
      pka[0] = cvtpk(a0, a1); pka[1] = cvtpk(a2, a3);
      pka[2] = cvtpk(a4, a5); pka[3] = cvtpk(a6, a7);
      short8 pa = *(short8*)&pka;

      float b0 = __expf(sb0[0]), b1 = __expf(sb0[1]), b2 = __expf(sb0[2]), b3 = __expf(sb0[3]);
      float b4 = __expf(sb1[0]), b5 = __expf(sb1[1]), b6 = __expf(sb1[2]), b7 = __expf(sb1[3]);
      lsb += (b0 + b1) + (b2 + b3) + (b4 + b5) + (b6 + b7);
      u32x4 pkb;
      pkb[0] = cvtpk(b0, b1); pkb[1] = cvtpk(b2, b3);
      pkb[2] = cvtpk(b4, b5); pkb[3] = cvtpk(b6, b7);
      short8 pbv = *(short8*)&pkb;

#pragma unroll
      for (int cs = 0; cs < 4; ++cs) {
        int row = cs * 16 + l15;
        short8 vf = *(const short8*)(vb + row * 64 + (((4 * s + g) ^ SW(row)) * 8));
        acca[cs] = __builtin_amdgcn_mfma_f32_16x16x32_bf16(vf, pa, acca[cs], 0, 0, 0);
        accb[cs] = __builtin_amdgcn_mfma_f32_16x16x32_bf16(vf, pbv, accb[cs], 0, 0, 0);
      }
    }

    if (t < 15) {
      unsigned short* kw_ = &kls[(t + 1) & 1][0][0];
      unsigned short* vw_ = &vls[(t + 1) & 1][0][0];
      *(short8*)(kw_ + wa0) = kg0;
      *(short8*)(kw_ + wa1) = kg1;
      *(short8*)(vw_ + wa0) = vg0;
      *(short8*)(vw_ + wa1) = vg1;
    }
    __syncthreads();
  }

  lsa += __shfl_xor(lsa, 16, 64);
  lsa += __shfl_xor(lsa, 32, 64);
  lsb += __shfl_xor(lsb, 16, 64);
  lsb += __shfl_xor(lsb, 32, 64);

  size_t sb_ = ((size_t)split * BATCH + b) * NPIX;
  unsigned short* Oba = OPb + (sb_ + nbase + l15) * 64;
  unsigned short* Obb = OPb + (sb_ + nbase + 16 + l15) * 64;
#pragma unroll
  for (int cs = 0; cs < 4; ++cs) {
    us4 va, vbq;
#pragma unroll
    for (int r = 0; r < 4; ++r) { va[r] = f2bf(acca[cs][r]); vbq[r] = f2bf(accb[cs][r]); }
    *(us4*)(Oba + cs * 16 + 4 * g) = va;
    *(us4*)(Obb + cs * 16 + 4 * g) = vbq;
  }
  if (g == 0) {
    LS[sb_ + nbase + l15] = lsa;
    LS[sb_ + nbase + 16 + l15] = lsb;
  }
}
#undef SW

// ------------- K4: reduce + proj GEMM + LN2 + BOTH branch GEMMs, fused --------
__global__ __launch_bounds__(256) void k_proj_ln2_pw(
    const unsigned short* __restrict__ OPb, const float* __restrict__ LSv,
    const float* __restrict__ x,
    const float* __restrict__ ow, const float* __restrict__ ob,
    const float* __restrict__ lg, const float* __restrict__ lb,
    const float* __restrict__ w1, const float* __restrict__ bb1,
    const float* __restrict__ w2, const float* __restrict__ bb2,
    float* __restrict__ xatt, float* __restrict__ t1, float* __restrict__ t2)
{
  __shared__ unsigned short aT[64][64];        // [px][ch] bf16, chunk-swizzled
  __shared__ float sm1[4][4][16], sm2[4][4][16];
  int tid = threadIdx.x;
  int b = blockIdx.y, pxb = blockIdx.x * 64;

  // phase 0: coalesced split-reduce + normalize -> swizzled LDS tile
#pragma unroll
  for (int h = 0; h < 2; ++h) {
    int off = (h * 256 + tid) * 8;
    int px = off >> 6;
    float sv[8] = {0.f, 0.f, 0.f, 0.f, 0.f, 0.f, 0.f, 0.f};
    float ls = 0.f;
#pragma unroll
    for (int sp = 0; sp < NSPLIT; ++sp) {
      size_t sbase = ((size_t)(sp * BATCH + b) * NPIX + pxb);
      short8 a = *(const short8*)(OPb + sbase * 64 + off);
#pragma unroll
      for (int j = 0; j < 8; ++j) sv[j] += bf2f((unsigned short)a[j]);
      ls += LSv[sbase + px];
    }
    float inv = 1.f / ls;
    unsigned short t[8];
#pragma unroll
    for (int j = 0; j < 8; ++j) t[j] = f2bf(sv[j] * inv);
    *(short8*)&aT[px][(((tid & 7) ^ (px & 7)) * 8)] = *(short8*)t;
  }
  __syncthreads();

  // phase 1: proj GEMM from LDS + residual + LN2 (xn2 -> back into aT)
  int wid = tid >> 6, lane = tid & 63;
  int l15 = lane & 15, g = lane >> 4;

  short8 af[2];
#pragma unroll
  for (int kc = 0; kc < 2; ++kc) {
    const float* wp = ow + (size_t)(wid * 16 + l15) * 64 + kc * 32 + 8 * g;
    unsigned short t[8];
#pragma unroll
    for (int j = 0; j < 8; ++j) t[j] = f2bf(wp[j]);
    af[kc] = *(short8*)t;
  }
  float bv[4], lgv[4], lbv[4];
#pragma unroll
  for (int r = 0; r < 4; ++r) {
    int o = wid * 16 + 4 * g + r;
    bv[r] = ob[o]; lgv[r] = lg[o]; lbv[r] = lb[o];
  }
  f32x4 acc[4];
#pragma unroll
  for (int ct = 0; ct < 4; ++ct) acc[ct] = (f32x4){bv[0], bv[1], bv[2], bv[3]};
#pragma unroll
  for (int ct = 0; ct < 4; ++ct) {
    int row = ct * 16 + l15;
    short8 bf0 = *(const short8*)&aT[row][(((0 + g) ^ (row & 7)) * 8)];
    short8 bf1 = *(const short8*)&aT[row][(((4 + g) ^ (row & 7)) * 8)];
    acc[ct] = __builtin_amdgcn_mfma_f32_16x16x32_bf16(af[0], bf0, acc[ct], 0, 0, 0);
    acc[ct] = __builtin_amdgcn_mfma_f32_16x16x32_bf16(af[1], bf1, acc[ct], 0, 0, 0);
  }

  float xo[4][4];
#pragma unroll
  for (int ct = 0; ct < 4; ++ct) {
    int p = pxb + ct * 16 + l15;
    float s1 = 0.f, s2 = 0.f;
#pragma unroll
    for (int r = 0; r < 4; ++r) {
      int o = wid * 16 + 4 * g + r;
      size_t oi = ((size_t)b * CH + o) * NPIX + p;
      float v = acc[ct][r] + x[oi];
      xatt[oi] = v;
      xo[ct][r] = v;
      s1 += v; s2 += v * v;
    }
    s1 += __shfl_xor(s1, 16, 64); s1 += __shfl_xor(s1, 32, 64);
    s2 += __shfl_xor(s2, 16, 64); s2 += __shfl_xor(s2, 32, 64);
    if (g == 0) { sm1[wid][ct][l15] = s1; sm2[wid][ct][l15] = s2; }
  }
  __syncthreads();   // all aT reads (phase1) complete before overwrite below
  {
    int ckid = (wid * 16 + 4 * g) >> 3;
    int coff = (4 * g) & 7;
#pragma unroll
    for (int ct = 0; ct < 4; ++ct) {
      int row = ct * 16 + l15;
      float mu = (sm1[0][ct][l15] + sm1[1][ct][l15] + sm1[2][ct][l15] + sm1[3][ct][l15]) * (1.f / 64.f);
      float ms = (sm2[0][ct][l15] + sm2[1][ct][l15] + sm2[2][ct][l15] + sm2[3][ct][l15]) * (1.f / 64.f);
      float rs = rsqrtf(ms - mu * mu + 1e-5f);
      us4 v4;
#pragma unroll
      for (int r = 0; r < 4; ++r) v4[r] = f2bf((xo[ct][r] - mu) * rs * lgv[r] + lbv[r]);
      *(us4*)&aT[row][((ckid ^ (row & 7)) * 8) + coff] = v4;
    }
  }

  // phase 2 weight frags (loads overlap the barrier wait)
  const float* W2  = (wid & 2) ? w2 : w1;
  const float* bb2_ = (wid & 2) ? bb2 : bb1;
  float* tdst      = (wid & 2) ? t2 : t1;
  int oh = (wid & 1) * 64;
  short8 af2[4][2];
#pragma unroll
  for (int ot = 0; ot < 4; ++ot)
#pragma unroll
    for (int kc = 0; kc < 2; ++kc) {
      const float* wp = W2 + (size_t)(oh + ot * 16 + l15) * 64 + kc * 32 + 8 * g;
      unsigned short tt[8];
#pragma unroll
      for (int j = 0; j < 8; ++j) tt[j] = f2bf(wp[j]);
      af2[ot][kc] = *(short8*)tt;
    }
  __syncthreads();   // xn2 tile complete

  // phase 2: both branch 1x1 GEMMs from the xn2 LDS tile
  f32x4 acc2[4][4];
#pragma unroll
  for (int ot = 0; ot < 4; ++ot) {
    float b0 = bb2_[oh + ot * 16 + 4 * g + 0];
    float b1 = bb2_[oh + ot * 16 + 4 * g + 1];
    float b2 = bb2_[oh + ot * 16 + 4 * g + 2];
    float b3 = bb2_[oh + ot * 16 + 4 * g + 3];
#pragma unroll
    for (int ct = 0; ct < 4; ++ct) acc2[ot][ct] = (f32x4){b0, b1, b2, b3};
  }
#pragma unroll
  for (int ct = 0; ct < 4; ++ct) {
    int row = ct * 16 + l15;
    short8 bf0 = *(const short8*)&aT[row][(((0 + g) ^ (row & 7)) * 8)];
    short8 bf1 = *(const short8*)&aT[row][(((4 + g) ^ (row & 7)) * 8)];
#pragma unroll
    for (int ot = 0; ot < 4; ++ot) {
      acc2[ot][ct] = __builtin_amdgcn_mfma_f32_16x16x32_bf16(af2[ot][0], bf0, acc2[ot][ct], 0, 0, 0);
      acc2[ot][ct] = __builtin_amdgcn_mfma_f32_16x16x32_bf16(af2[ot][1], bf1, acc2[ot][ct], 0, 0, 0);
    }
  }
#pragma unroll
  for (int ot = 0; ot < 4; ++ot)
#pragma unroll
    for (int ct = 0; ct < 4; ++ct) {
      int p = pxb + ct * 16 + l15;
#pragma unroll
      for (int r = 0; r < 4; ++r) {
        int o = oh + ot * 16 + 4 * g + r;
        tdst[((size_t)b * 128 + o) * NPIX + p] = acc2[ot][ct][r];
      }
    }
}

// ------------- K5: dw3x3+gelu+gate (phase A) + final GEMM + residual (B) ------
// Block = (image row h, batch b). Phase A: 4 waves x (px, 32ch) compute the
// gated-gelu tile into chunk-swizzled LDS [px][128ch]. Phase B: k_out GEMM.
__global__ __launch_bounds__(256) void k_dwgelu_out(
    const float* __restrict__ t1, const float* __restrict__ t2,
    const float* __restrict__ w1, const float* __restrict__ bb1,
    const float* __restrict__ w2, const float* __restrict__ bb2,
    const float* __restrict__ W, const float* __restrict__ bias,
    const float* __restrict__ res, float* __restrict__ outF)
{
  __shared__ unsigned short gT[64][128];       // [px][ch] bf16, chunk-swizzled
  int tid = threadIdx.x;
  int b = blockIdx.y;
  int hrow = blockIdx.x;                       // image row (0..63)
  int pxb = hrow * 64;
  int px = tid & 63, cg = tid >> 6;            // pixel-in-row, channel group

  // phase B weight frags first (global loads overlap phase A compute)
  int wid = tid >> 6, lane = tid & 63;
  int l15 = lane & 15, g = lane >> 4;
  short8 af[4];
#pragma unroll
  for (int kc = 0; kc < 4; ++kc) {
    const float* wp = W + (size_t)(wid * 16 + l15) * 128 + kc * 32 + 8 * g;
    unsigned short t[8];
#pragma unroll
    for (int j = 0; j < 8; ++j) t[j] = f2bf(wp[j]);
    af[kc] = *(short8*)t;
  }
  float bv[4];
#pragma unroll
  for (int r = 0; r < 4; ++r) bv[r] = bias[wid * 16 + 4 * g + r];

  // ---- phase A: dw3x3 + gelu + gate for channels cg*32..+31, pixel px ----
  {
    int w = px;
    bool okm = hrow > 0, okp = hrow < 63;      // wave-uniform row bounds
    bool okl = w > 0, okr = w < 63;
#pragma unroll
    for (int jc = 0; jc < 32; jc += 4) {
      us4 outv;
#pragma unroll
      for (int q = 0; q < 4; ++q) {
        int c = cg * 32 + jc + q;              // wave-uniform channel
        const float* s1 = t1 + ((size_t)b * 128 + c) * NPIX + hrow * 64 + w;
        const float* s2 = t2 + ((size_t)b * 128 + c) * NPIX + hrow * 64 + w;
        const float* w1c = w1 + c * 9;
        const float* w2c = w2 + c * 9;
        float a1 = bb1[c], a2 = bb2[c];
#pragma unroll
        for (int dy = -1; dy <= 1; ++dy) {
          bool oky = (dy == 0) || (dy < 0 ? okm : okp);
          int ro = dy * 64;
#pragma unroll
          for (int dx = -1; dx <= 1; ++dx) {
            bool ok = oky && ((dx == 0) || (dx < 0 ? okl : okr));
            float v1 = ok ? s1[ro + dx] : 0.f;
            float v2 = ok ? s2[ro + dx] : 0.f;
            int t = (dy + 1) * 3 + (dx + 1);
            a1 += w1c[t] * v1;
            a2 += w2c[t] * v2;
          }
        }
        float ge1 = 0.5f * a1 * (1.f + erff(a1 * 0.70710678118654752f));
        float ge2 = 0.5f * a2 * (1.f + erff(a2 * 0.70710678118654752f));
        outv[q] = f2bf(ge1 * ge2);
      }
      int ch0 = cg * 32 + jc;
      int ck = ch0 >> 3, coff = ch0 & 7;       // chunk in [0,16), offset 0/4
      *(us4*)&gT[px][((ck ^ (px & 7)) * 8) + coff] = outv;
    }
  }
  __syncthreads();

  // ---- phase B: out GEMM 64oc x 64px from LDS + residual ----
#pragma unroll
  for (int ct = 0; ct < 4; ++ct) {
    f32x4 acc = {bv[0], bv[1], bv[2], bv[3]};
    int row = ct * 16 + l15;
#pragma unroll
    for (int kc = 0; kc < 4; ++kc) {
      int ckr = kc * 4 + g;
      short8 bf = *(const short8*)&gT[row][((ckr ^ (row & 7)) * 8)];
      acc = __builtin_amdgcn_mfma_f32_16x16x32_bf16(af[kc], bf, acc, 0, 0, 0);
    }
    int p = pxb + row;
#pragma unroll
    for (int r = 0; r < 4; ++r) {
      int o = wid * 16 + 4 * g + r;
      size_t oi = ((size_t)b * CH + o) * NPIX + p;
      outF[oi] = acc[r] + res[oi];
    }
  }
}

extern "C" void kernel_launch(void* const* d_in, const int* in_sizes, int n_in,
                              void* d_out, int out_size, void* d_ws, size_t ws_size,
                              hipStream_t stream) {
  const float* x        = (const float*)d_in[0];
  const float* cta_ln_g = (const float*)d_in[1];
  const float* cta_ln_b = (const float*)d_in[2];
  const float* q_w      = (const float*)d_in[3];
  const float* q_b      = (const float*)d_in[4];
  const float* k_w      = (const float*)d_in[5];
  const float* k_b      = (const float*)d_in[6];
  const float* v_w      = (const float*)d_in[7];
  const float* v_b      = (const float*)d_in[8];
  const float* cta_out_w= (const float*)d_in[9];
  const float* cta_out_b= (const float*)d_in[10];
  const float* nle_ln_g = (const float*)d_in[11];
  const float* nle_ln_b = (const float*)d_in[12];
  const float* b1_w1    = (const float*)d_in[13];
  const float* b1_b1    = (const float*)d_in[14];
  const float* b1_w2    = (const float*)d_in[15];
  const float* b1_b2    = (const float*)d_in[16];
  const float* b2_w1    = (const float*)d_in[17];
  const float* b2_b1    = (const float*)d_in[18];
  const float* b2_w2    = (const float*)d_in[19];
  const float* b2_b2    = (const float*)d_in[20];
  const float* nle_out_w= (const float*)d_in[21];
  const float* nle_out_b= (const float*)d_in[22];

  char* ws = (char*)d_ws;
  float*          xn   = (float*)(ws);                         // 0..4MB
  unsigned short* Qb   = (unsigned short*)(ws + (4u  << 20));  // 4..6
  unsigned short* Kb   = (unsigned short*)(ws + (6u  << 20));  // 6..8
  unsigned short* VTb  = (unsigned short*)(ws + (8u  << 20));  // 8..10
  unsigned short* OPb  = (unsigned short*)(ws + (10u << 20));  // 10..18 (4 x 2MB)
  float*          LSb  = (float*)(ws + (18u << 20));           // 18..18.25
  float*          xatt = (float*)(ws + (21u << 20));           // 21..25
  float*          t1   = (float*)(ws + (27u << 20));           // 27..35
  float*          t2   = (float*)(ws + (35u << 20));           // 35..43

  k_ln_q        <<<256, 256, 0, stream>>>(x, cta_ln_g, cta_ln_b, q_w, q_b, xn, Qb);
  k_dwkv        <<<dim3(64, 8), 256, 0, stream>>>(xn, k_w, k_b, v_w, v_b, Kb, VTb);
  k_attn        <<<dim3(32, BATCH, NSPLIT), 256, 0, stream>>>(Qb, Kb, VTb, OPb, LSb);
  k_proj_ln2_pw <<<dim3(64, 4), 256, 0, stream>>>(OPb, LSb, x, cta_out_w, cta_out_b,
                                                  nle_ln_g, nle_ln_b,
                                                  b1_w1, b1_b1, b2_w1, b2_b1,
                                                  xatt, t1, t2);
  k_dwgelu_out  <<<dim3(64, 4), 256, 0, stream>>>(t1, t2, b1_w2, b1_b2, b2_w2, b2_b2,
                                                  nle_out_w, nle_out_b, xatt, (float*)d_out);
}

// Round 20
// 70.547 us; speedup vs baseline: 1.1826x; 1.1826x over previous
//
#include <hip/hip_runtime.h>
#include <hip/hip_bf16.h>
#include <math.h>

#define NPIX 4096
#define CH 64
#define BATCH 4
#define NSPLIT 4

typedef __attribute__((ext_vector_type(8))) short short8;
typedef __attribute__((ext_vector_type(4))) float f32x4;
typedef __attribute__((ext_vector_type(4))) unsigned short us4;
typedef __attribute__((ext_vector_type(4))) unsigned int u32x4;

static __device__ __forceinline__ unsigned short f2bf(float f) {
  union { float f; unsigned u; } v; v.f = f;
  unsigned u = v.u;
  unsigned r = u + 0x7FFF + ((u >> 16) & 1);
  return (unsigned short)(r >> 16);
}
static __device__ __forceinline__ float bf2f(unsigned short u) {
  union { unsigned u; float f; } v; v.u = ((unsigned)u) << 16; return v.f;
}
static __device__ __forceinline__ unsigned cvtpk(float lo, float hi) {
  unsigned r;
  asm("v_cvt_pk_bf16_f32 %0, %1, %2" : "=v"(r) : "v"(lo), "v"(hi));
  return r;
}

// ---------------- K1: LayerNorm(C) + q-proj MFMA GEMM, fused ------------------
__global__ __launch_bounds__(256) void k_ln_q(
    const float* __restrict__ x, const float* __restrict__ lg, const float* __restrict__ lb,
    const float* __restrict__ qw, const float* __restrict__ qb,
    float* __restrict__ xn, unsigned short* __restrict__ Q)
{
  __shared__ float xT[64][64];                 // [c][px] f32
  __shared__ unsigned short xB[64][64];        // [px][c] bf16, chunk-swizzled
  int tid = threadIdx.x, px = tid & 63, g4 = tid >> 6;
  int idx0 = blockIdx.x * 64;
  int idx = idx0 + px;
  int b = idx >> 12, p = idx & 4095;
  const float* xb = x + (size_t)b * CH * NPIX + p;
  for (int j = 0; j < 16; ++j) { int c = 16 * g4 + j; xT[c][px] = xb[(size_t)c * NPIX]; }
  __syncthreads();
  float xv[64]; float s = 0.f;
#pragma unroll
  for (int c = 0; c < 64; ++c) { xv[c] = xT[c][px]; s += xv[c]; }
  float mu = s * (1.f / 64.f), vs = 0.f;
#pragma unroll
  for (int c = 0; c < 64; ++c) { float d = xv[c] - mu; vs += d * d; }
  float rs = rsqrtf(vs * (1.f / 64.f) + 1e-5f);
#pragma unroll
  for (int c = 0; c < 64; ++c) xv[c] = (xv[c] - mu) * rs * lg[c] + lb[c];

  float* xnb = xn + (size_t)b * CH * NPIX + p;
#define LNQ_WR(C0)                                                             \
  {                                                                            \
    unsigned short t[16];                                                      \
    _Pragma("unroll") for (int j = 0; j < 16; ++j) {                           \
      float v = xv[C0 + j];                                                    \
      xnb[(size_t)(C0 + j) * NPIX] = v;                                        \
      t[j] = f2bf(v);                                                          \
    }                                                                          \
    *(short8*)&xB[px][(((C0 / 8) + 0) ^ (px & 7)) * 8] = *(short8*)t;          \
    *(short8*)&xB[px][(((C0 / 8) + 1) ^ (px & 7)) * 8] = *(short8*)(t + 8);    \
  }
  if (g4 == 0) LNQ_WR(0)
  else if (g4 == 1) LNQ_WR(16)
  else if (g4 == 2) LNQ_WR(32)
  else LNQ_WR(48)
#undef LNQ_WR
  __syncthreads();

  int lane = tid & 63, l15 = lane & 15, gg = lane >> 4;
  short8 af[2];
#pragma unroll
  for (int kc = 0; kc < 2; ++kc) {
    const float* wp = qw + (size_t)(g4 * 16 + l15) * 64 + kc * 32 + 8 * gg;
    unsigned short t[8];
#pragma unroll
    for (int j = 0; j < 8; ++j) t[j] = f2bf(wp[j]);
    af[kc] = *(short8*)t;
  }
  float bv[4];
#pragma unroll
  for (int r = 0; r < 4; ++r) bv[r] = qb[g4 * 16 + 4 * gg + r];
#pragma unroll
  for (int ct = 0; ct < 4; ++ct) {
    f32x4 acc = {bv[0], bv[1], bv[2], bv[3]};
    int row = ct * 16 + l15;
    short8 bf0 = *(const short8*)&xB[row][((0 + gg) ^ (row & 7)) * 8];
    short8 bf1 = *(const short8*)&xB[row][((4 + gg) ^ (row & 7)) * 8];
    acc = __builtin_amdgcn_mfma_f32_16x16x32_bf16(af[0], bf0, acc, 0, 0, 0);
    acc = __builtin_amdgcn_mfma_f32_16x16x32_bf16(af[1], bf1, acc, 0, 0, 0);
    us4 v;
#pragma unroll
    for (int r = 0; r < 4; ++r) v[r] = f2bf(acc[r] * 0.125f);
    *(us4*)(Q + (size_t)(idx0 + row) * 64 + g4 * 16 + 4 * gg) = v;
  }
}

// ---------------- K2: depthwise 3x3 for k and v (channel-split) ---------------
__global__ __launch_bounds__(256) void k_dwkv(
    const float* __restrict__ xn,
    const float* __restrict__ kw, const float* __restrict__ kb,
    const float* __restrict__ vw, const float* __restrict__ vb,
    unsigned short* __restrict__ K, unsigned short* __restrict__ VT)
{
  int idx = blockIdx.x * 256 + threadIdx.x;
  int b = idx >> 12, p = idx & 4095;
  int h = p >> 6, w = p & 63;
  int c0 = blockIdx.y * 8;
  size_t base = (size_t)b * CH * NPIX;
  unsigned short kq[8];
#pragma unroll
  for (int j = 0; j < 8; ++j) {
    int c = c0 + j;
    const float* xc = xn + base + (size_t)c * NPIX;
    float ka = kb[c], va = vb[c];
#pragma unroll
    for (int dy = -1; dy <= 1; ++dy) {
#pragma unroll
      for (int dx = -1; dx <= 1; ++dx) {
        int hh = h + dy, ww = w + dx;
        float xvv = (hh >= 0 && hh < 64 && ww >= 0 && ww < 64) ? xc[hh * 64 + ww] : 0.f;
        int t = (dy + 1) * 3 + (dx + 1);
        ka += kw[c * 9 + t] * xvv;
        va += vw[c * 9 + t] * xvv;
      }
    }
    kq[j] = f2bf(ka);
    VT[((size_t)b * CH + c) * NPIX + p] = f2bf(va);
  }
  *(short8*)(K + (size_t)idx * 64 + c0) = *(short8*)(kq);
}

// ---------------- K3: hybrid attention, 32 q-rows/wave ------------------------
#define SW(r) ((((r) & 7) ^ (((r) >> 3) << 1)) & 7)
__global__ __launch_bounds__(256, 4) void k_attn(
    const unsigned short* __restrict__ Q, const unsigned short* __restrict__ K,
    const unsigned short* __restrict__ VT, unsigned short* __restrict__ OPb,
    float* __restrict__ LS)
{
  __shared__ unsigned short kls[2][64][64];
  __shared__ unsigned short vls[2][64][64];

  int tid = threadIdx.x;
  int wid = tid >> 6, lane = tid & 63;
  int l15 = lane & 15, g = lane >> 4;
  int b = blockIdx.y, split = blockIdx.z;
  int nbase = blockIdx.x * 128 + wid * 32;

  const unsigned short* Qb = Q + (size_t)b * NPIX * CH;
  const unsigned short* Kb = K + (size_t)b * NPIX * CH;
  const unsigned short* Vb = VT + (size_t)b * CH * NPIX;

  short8 qf0a = *(const short8*)(Qb + (size_t)(nbase + l15) * CH + 8 * g);
  short8 qf1a = *(const short8*)(Qb + (size_t)(nbase + l15) * CH + 32 + 8 * g);
  short8 qf0b = *(const short8*)(Qb + (size_t)(nbase + 16 + l15) * CH + 8 * g);
  short8 qf1b = *(const short8*)(Qb + (size_t)(nbase + 16 + l15) * CH + 32 + 8 * g);

  f32x4 acca[4], accb[4];
#pragma unroll
  for (int i = 0; i < 4; ++i) {
    acca[i] = (f32x4){0.f, 0.f, 0.f, 0.f};
    accb[i] = (f32x4){0.f, 0.f, 0.f, 0.f};
  }
  float lsa = 0.f, lsb = 0.f;

  int srow = tid >> 3, sch = tid & 7;
  int srow1 = srow + 32;
  int wa0 = srow * 64 + ((sch ^ SW(srow)) * 8);
  int wa1 = srow1 * 64 + ((sch ^ SW(srow1)) * 8);
  const unsigned short* ksrc0 = Kb + (size_t)(split * 1024 + srow) * CH + sch * 8;
  const unsigned short* ksrc1 = Kb + (size_t)(split * 1024 + srow1) * CH + sch * 8;
  const unsigned short* vsrc0 = Vb + (size_t)srow * NPIX + split * 1024 + sch * 8;
  const unsigned short* vsrc1 = Vb + (size_t)srow1 * NPIX + split * 1024 + sch * 8;

  int kperm = 8 * (l15 >> 2) + (l15 & 3);

  short8 kg0, kg1, vg0, vg1;
  kg0 = *(const short8*)(ksrc0);
  kg1 = *(const short8*)(ksrc1);
  vg0 = *(const short8*)(vsrc0);
  vg1 = *(const short8*)(vsrc1);
  *(short8*)(&kls[0][0][0] + wa0) = kg0;
  *(short8*)(&kls[0][0][0] + wa1) = kg1;
  *(short8*)(&vls[0][0][0] + wa0) = vg0;
  *(short8*)(&vls[0][0][0] + wa1) = vg1;
  __syncthreads();

  for (int t = 0; t < 16; ++t) {
    if (t < 15) {
      int ko = (t + 1) * 64;
      kg0 = *(const short8*)(ksrc0 + (size_t)ko * CH);
      kg1 = *(const short8*)(ksrc1 + (size_t)ko * CH);
      vg0 = *(const short8*)(vsrc0 + ko);
      vg1 = *(const short8*)(vsrc1 + ko);
    }

    const unsigned short* kb = &kls[t & 1][0][0];
    const unsigned short* vb = &vls[t & 1][0][0];

#pragma unroll
    for (int s = 0; s < 2; ++s) {
      int r0 = s * 32 + kperm;
      int r1 = s * 32 + 4 + kperm;
      short8 kf00 = *(const short8*)(kb + r0 * 64 + (((0 + g) ^ SW(r0)) * 8));
      short8 kf01 = *(const short8*)(kb + r0 * 64 + (((4 + g) ^ SW(r0)) * 8));
      short8 kf10 = *(const short8*)(kb + r1 * 64 + (((0 + g) ^ SW(r1)) * 8));
      short8 kf11 = *(const short8*)(kb + r1 * 64 + (((4 + g) ^ SW(r1)) * 8));
      f32x4 sa0 = {0.f,0.f,0.f,0.f}, sa1 = {0.f,0.f,0.f,0.f};
      f32x4 sb0 = {0.f,0.f,0.f,0.f}, sb1 = {0.f,0.f,0.f,0.f};
      sa0 = __builtin_amdgcn_mfma_f32_16x16x32_bf16(kf00, qf0a, sa0, 0, 0, 0);
      sa0 = __builtin_amdgcn_mfma_f32_16x16x32_bf16(kf01, qf1a, sa0, 0, 0, 0);
      sa1 = __builtin_amdgcn_mfma_f32_16x16x32_bf16(kf10, qf0a, sa1, 0, 0, 0);
      sa1 = __builtin_amdgcn_mfma_f32_16x16x32_bf16(kf11, qf1a, sa1, 0, 0, 0);
      sb0 = __builtin_amdgcn_mfma_f32_16x16x32_bf16(kf00, qf0b, sb0, 0, 0, 0);
      sb0 = __builtin_amdgcn_mfma_f32_16x16x32_bf16(kf01, qf1b, sb0, 0, 0, 0);
      sb1 = __builtin_amdgcn_mfma_f32_16x16x32_bf16(kf10, qf0b, sb1, 0, 0, 0);
      sb1 = __builtin_amdgcn_mfma_f32_16x16x32_bf16(kf11, qf1b, sb1, 0, 0, 0);

      float a0 = __expf(sa0[0]), a1 = __expf(sa0[1]), a2 = __expf(sa0[2]), a3 = __expf(sa0[3]);
      float a4 = __expf(sa1[0]), a5 = __expf(sa1[1]), a6 = __expf(sa1[2]), a7 = __expf(sa1[3]);
      lsa += (a0 + a1) + (a2 + a3) + (a4 + a5) + (a6 + a7);
      u32x4 pka;
      pka[0] = cvtpk(a0, a1); pka[1] = cvtpk(a2, a3);
      pka[2] = cvtpk(a4, a5); pka[3] = cvtpk(a6, a7);
      short8 pa = *(short8*)&pka;

      float b0 = __expf(sb0[0]), b1 = __expf(sb0[1]), b2 = __expf(sb0[2]), b3 = __expf(sb0[3]);
      float b4 = __expf(sb1[0]), b5 = __expf(sb1[1]), b6 = __expf(sb1[2]), b7 = __expf(sb1[3]);
      lsb += (b0 + b1) + (b2 + b3) + (b4 + b5) + (b6 + b7);
      u32x4 pkb;
      pkb[0] = cvtpk(b0, b1); pkb[1] = cvtpk(b2, b3);
      pkb[2] = cvtpk(b4, b5); pkb[3] = cvtpk(b6, b7);
      short8 pbv = *(short8*)&pkb;

#pragma unroll
      for (int cs = 0; cs < 4; ++cs) {
        int row = cs * 16 + l15;
        short8 vf = *(const short8*)(vb + row * 64 + (((4 * s + g) ^ SW(row)) * 8));
        acca[cs] = __builtin_amdgcn_mfma_f32_16x16x32_bf16(vf, pa, acca[cs], 0, 0, 0);
        accb[cs] = __builtin_amdgcn_mfma_f32_16x16x32_bf16(vf, pbv, accb[cs], 0, 0, 0);
      }
    }

    if (t < 15) {
      unsigned short* kw_ = &kls[(t + 1) & 1][0][0];
      unsigned short* vw_ = &vls[(t + 1) & 1][0][0];
      *(short8*)(kw_ + wa0) = kg0;
      *(short8*)(kw_ + wa1) = kg1;
      *(short8*)(vw_ + wa0) = vg0;
      *(short8*)(vw_ + wa1) = vg1;
    }
    __syncthreads();
  }

  lsa += __shfl_xor(lsa, 16, 64);
  lsa += __shfl_xor(lsa, 32, 64);
  lsb += __shfl_xor(lsb, 16, 64);
  lsb += __shfl_xor(lsb, 32, 64);

  size_t sb_ = ((size_t)split * BATCH + b) * NPIX;
  unsigned short* Oba = OPb + (sb_ + nbase + l15) * 64;
  unsigned short* Obb = OPb + (sb_ + nbase + 16 + l15) * 64;
#pragma unroll
  for (int cs = 0; cs < 4; ++cs) {
    us4 va, vbq;
#pragma unroll
    for (int r = 0; r < 4; ++r) { va[r] = f2bf(acca[cs][r]); vbq[r] = f2bf(accb[cs][r]); }
    *(us4*)(Oba + cs * 16 + 4 * g) = va;
    *(us4*)(Obb + cs * 16 + 4 * g) = vbq;
  }
  if (g == 0) {
    LS[sb_ + nbase + l15] = lsa;
    LS[sb_ + nbase + 16 + l15] = lsb;
  }
}
#undef SW

// ------------- K4: reduce + proj GEMM + LN2 + BOTH branch GEMMs, fused --------
__global__ __launch_bounds__(256) void k_proj_ln2_pw(
    const unsigned short* __restrict__ OPb, const float* __restrict__ LSv,
    const float* __restrict__ x,
    const float* __restrict__ ow, const float* __restrict__ ob,
    const float* __restrict__ lg, const float* __restrict__ lb,
    const float* __restrict__ w1, const float* __restrict__ bb1,
    const float* __restrict__ w2, const float* __restrict__ bb2,
    float* __restrict__ xatt, float* __restrict__ t1, float* __restrict__ t2)
{
  __shared__ unsigned short aT[64][64];        // [px][ch] bf16, chunk-swizzled
  __shared__ float sm1[4][4][16], sm2[4][4][16];
  int tid = threadIdx.x;
  int b = blockIdx.y, pxb = blockIdx.x * 64;

  // phase 0: coalesced split-reduce + normalize -> swizzled LDS tile
#pragma unroll
  for (int h = 0; h < 2; ++h) {
    int off = (h * 256 + tid) * 8;
    int px = off >> 6;
    float sv[8] = {0.f, 0.f, 0.f, 0.f, 0.f, 0.f, 0.f, 0.f};
    float ls = 0.f;
#pragma unroll
    for (int sp = 0; sp < NSPLIT; ++sp) {
      size_t sbase = ((size_t)(sp * BATCH + b) * NPIX + pxb);
      short8 a = *(const short8*)(OPb + sbase * 64 + off);
#pragma unroll
      for (int j = 0; j < 8; ++j) sv[j] += bf2f((unsigned short)a[j]);
      ls += LSv[sbase + px];
    }
    float inv = 1.f / ls;
    unsigned short t[8];
#pragma unroll
    for (int j = 0; j < 8; ++j) t[j] = f2bf(sv[j] * inv);
    *(short8*)&aT[px][(((tid & 7) ^ (px & 7)) * 8)] = *(short8*)t;
  }
  __syncthreads();

  // phase 1: proj GEMM from LDS + residual + LN2 (xn2 -> back into aT)
  int wid = tid >> 6, lane = tid & 63;
  int l15 = lane & 15, g = lane >> 4;

  short8 af[2];
#pragma unroll
  for (int kc = 0; kc < 2; ++kc) {
    const float* wp = ow + (size_t)(wid * 16 + l15) * 64 + kc * 32 + 8 * g;
    unsigned short t[8];
#pragma unroll
    for (int j = 0; j < 8; ++j) t[j] = f2bf(wp[j]);
    af[kc] = *(short8*)t;
  }
  float bv[4], lgv[4], lbv[4];
#pragma unroll
  for (int r = 0; r < 4; ++r) {
    int o = wid * 16 + 4 * g + r;
    bv[r] = ob[o]; lgv[r] = lg[o]; lbv[r] = lb[o];
  }
  f32x4 acc[4];
#pragma unroll
  for (int ct = 0; ct < 4; ++ct) acc[ct] = (f32x4){bv[0], bv[1], bv[2], bv[3]};
#pragma unroll
  for (int ct = 0; ct < 4; ++ct) {
    int row = ct * 16 + l15;
    short8 bf0 = *(const short8*)&aT[row][(((0 + g) ^ (row & 7)) * 8)];
    short8 bf1 = *(const short8*)&aT[row][(((4 + g) ^ (row & 7)) * 8)];
    acc[ct] = __builtin_amdgcn_mfma_f32_16x16x32_bf16(af[0], bf0, acc[ct], 0, 0, 0);
    acc[ct] = __builtin_amdgcn_mfma_f32_16x16x32_bf16(af[1], bf1, acc[ct], 0, 0, 0);
  }

  float xo[4][4];
#pragma unroll
  for (int ct = 0; ct < 4; ++ct) {
    int p = pxb + ct * 16 + l15;
    float s1 = 0.f, s2 = 0.f;
#pragma unroll
    for (int r = 0; r < 4; ++r) {
      int o = wid * 16 + 4 * g + r;
      size_t oi = ((size_t)b * CH + o) * NPIX + p;
      float v = acc[ct][r] + x[oi];
      xatt[oi] = v;
      xo[ct][r] = v;
      s1 += v; s2 += v * v;
    }
    s1 += __shfl_xor(s1, 16, 64); s1 += __shfl_xor(s1, 32, 64);
    s2 += __shfl_xor(s2, 16, 64); s2 += __shfl_xor(s2, 32, 64);
    if (g == 0) { sm1[wid][ct][l15] = s1; sm2[wid][ct][l15] = s2; }
  }
  __syncthreads();   // all aT reads (phase1) complete before overwrite below
  {
    int ckid = (wid * 16 + 4 * g) >> 3;
    int coff = (4 * g) & 7;
#pragma unroll
    for (int ct = 0; ct < 4; ++ct) {
      int row = ct * 16 + l15;
      float mu = (sm1[0][ct][l15] + sm1[1][ct][l15] + sm1[2][ct][l15] + sm1[3][ct][l15]) * (1.f / 64.f);
      float ms = (sm2[0][ct][l15] + sm2[1][ct][l15] + sm2[2][ct][l15] + sm2[3][ct][l15]) * (1.f / 64.f);
      float rs = rsqrtf(ms - mu * mu + 1e-5f);
      us4 v4;
#pragma unroll
      for (int r = 0; r < 4; ++r) v4[r] = f2bf((xo[ct][r] - mu) * rs * lgv[r] + lbv[r]);
      *(us4*)&aT[row][((ckid ^ (row & 7)) * 8) + coff] = v4;
    }
  }

  // phase 2 weight frags (loads overlap the barrier wait)
  const float* W2  = (wid & 2) ? w2 : w1;
  const float* bb2_ = (wid & 2) ? bb2 : bb1;
  float* tdst      = (wid & 2) ? t2 : t1;
  int oh = (wid & 1) * 64;
  short8 af2[4][2];
#pragma unroll
  for (int ot = 0; ot < 4; ++ot)
#pragma unroll
    for (int kc = 0; kc < 2; ++kc) {
      const float* wp = W2 + (size_t)(oh + ot * 16 + l15) * 64 + kc * 32 + 8 * g;
      unsigned short tt[8];
#pragma unroll
      for (int j = 0; j < 8; ++j) tt[j] = f2bf(wp[j]);
      af2[ot][kc] = *(short8*)tt;
    }
  __syncthreads();   // xn2 tile complete

  // phase 2: both branch 1x1 GEMMs from the xn2 LDS tile
  f32x4 acc2[4][4];
#pragma unroll
  for (int ot = 0; ot < 4; ++ot) {
    float b0 = bb2_[oh + ot * 16 + 4 * g + 0];
    float b1 = bb2_[oh + ot * 16 + 4 * g + 1];
    float b2 = bb2_[oh + ot * 16 + 4 * g + 2];
    float b3 = bb2_[oh + ot * 16 + 4 * g + 3];
#pragma unroll
    for (int ct = 0; ct < 4; ++ct) acc2[ot][ct] = (f32x4){b0, b1, b2, b3};
  }
#pragma unroll
  for (int ct = 0; ct < 4; ++ct) {
    int row = ct * 16 + l15;
    short8 bf0 = *(const short8*)&aT[row][(((0 + g) ^ (row & 7)) * 8)];
    short8 bf1 = *(const short8*)&aT[row][(((4 + g) ^ (row & 7)) * 8)];
#pragma unroll
    for (int ot = 0; ot < 4; ++ot) {
      acc2[ot][ct] = __builtin_amdgcn_mfma_f32_16x16x32_bf16(af2[ot][0], bf0, acc2[ot][ct], 0, 0, 0);
      acc2[ot][ct] = __builtin_amdgcn_mfma_f32_16x16x32_bf16(af2[ot][1], bf1, acc2[ot][ct], 0, 0, 0);
    }
  }
#pragma unroll
  for (int ot = 0; ot < 4; ++ot)
#pragma unroll
    for (int ct = 0; ct < 4; ++ct) {
      int p = pxb + ct * 16 + l15;
#pragma unroll
      for (int r = 0; r < 4; ++r) {
        int o = oh + ot * 16 + 4 * g + r;
        tdst[((size_t)b * 128 + o) * NPIX + p] = acc2[ot][ct][r];
      }
    }
}

// ------------- K5: dw3x3 + gelu + gate -> g12T bf16 ---------------------------
__global__ __launch_bounds__(256) void k_dwgelu(
    const float* __restrict__ t1, const float* __restrict__ t2,
    const float* __restrict__ w1, const float* __restrict__ bb1,
    const float* __restrict__ w2, const float* __restrict__ bb2,
    unsigned short* __restrict__ g12T)
{
  int idx = blockIdx.x * 256 + threadIdx.x;
  int b = idx >> 12, p = idx & 4095;
  int h = p >> 6, w = p & 63;
  int c0 = blockIdx.y * 8;
  unsigned short outv[8];
#pragma unroll
  for (int j = 0; j < 8; ++j) {
    int c = c0 + j;
    size_t tb = ((size_t)b * 128 + c) * NPIX;
    float a1 = bb1[c], a2 = bb2[c];
#pragma unroll
    for (int dy = -1; dy <= 1; ++dy) {
#pragma unroll
      for (int dx = -1; dx <= 1; ++dx) {
        int hh = h + dy, ww = w + dx;
        bool ok = (hh >= 0 && hh < 64 && ww >= 0 && ww < 64);
        float v1 = ok ? t1[tb + hh * 64 + ww] : 0.f;
        float v2 = ok ? t2[tb + hh * 64 + ww] : 0.f;
        int t = (dy + 1) * 3 + (dx + 1);
        a1 += w1[c * 9 + t] * v1;
        a2 += w2[c * 9 + t] * v2;
      }
    }
    float ge1 = 0.5f * a1 * (1.f + erff(a1 * 0.70710678118654752f));
    float ge2 = 0.5f * a2 * (1.f + erff(a2 * 0.70710678118654752f));
    outv[j] = f2bf(ge1 * ge2);
  }
  *(short8*)(g12T + (size_t)idx * 128 + c0) = *(short8*)outv;
}

// ------------- K6: final 1x1 (64x128) GEMM + residual -------------------------
__global__ __launch_bounds__(256) void k_out(
    const float* __restrict__ W, const float* __restrict__ bias,
    const unsigned short* __restrict__ InT, const float* __restrict__ res,
    float* __restrict__ outF)
{
  int tid = threadIdx.x;
  int wid = tid >> 6, lane = tid & 63;
  int l15 = lane & 15, g = lane >> 4;
  int b = blockIdx.y, pxb = blockIdx.x * 64;
  const unsigned short* In = InT + ((size_t)b * NPIX + pxb) * 128;

  short8 af[4];
#pragma unroll
  for (int kc = 0; kc < 4; ++kc) {
    const float* wp = W + (size_t)(wid * 16 + l15) * 128 + kc * 32 + 8 * g;
    unsigned short t[8];
#pragma unroll
    for (int j = 0; j < 8; ++j) t[j] = f2bf(wp[j]);
    af[kc] = *(short8*)t;
  }
  float bv[4];
#pragma unroll
  for (int r = 0; r < 4; ++r) bv[r] = bias[wid * 16 + 4 * g + r];
#pragma unroll
  for (int ct = 0; ct < 4; ++ct) {
    f32x4 acc = {bv[0], bv[1], bv[2], bv[3]};
#pragma unroll
    for (int kc = 0; kc < 4; ++kc) {
      short8 bf = *(const short8*)(In + (size_t)(ct * 16 + l15) * 128 + kc * 32 + 8 * g);
      acc = __builtin_amdgcn_mfma_f32_16x16x32_bf16(af[kc], bf, acc, 0, 0, 0);
    }
    int p = pxb + ct * 16 + l15;
#pragma unroll
    for (int r = 0; r < 4; ++r) {
      int o = wid * 16 + 4 * g + r;
      size_t oi = ((size_t)b * CH + o) * NPIX + p;
      outF[oi] = acc[r] + res[oi];
    }
  }
}

extern "C" void kernel_launch(void* const* d_in, const int* in_sizes, int n_in,
                              void* d_out, int out_size, void* d_ws, size_t ws_size,
                              hipStream_t stream) {
  const float* x        = (const float*)d_in[0];
  const float* cta_ln_g = (const float*)d_in[1];
  const float* cta_ln_b = (const float*)d_in[2];
  const float* q_w      = (const float*)d_in[3];
  const float* q_b      = (const float*)d_in[4];
  const float* k_w      = (const float*)d_in[5];
  const float* k_b      = (const float*)d_in[6];
  const float* v_w      = (const float*)d_in[7];
  const float* v_b      = (const float*)d_in[8];
  const float* cta_out_w= (const float*)d_in[9];
  const float* cta_out_b= (const float*)d_in[10];
  const float* nle_ln_g = (const float*)d_in[11];
  const float* nle_ln_b = (const float*)d_in[12];
  const float* b1_w1    = (const float*)d_in[13];
  const float* b1_b1    = (const float*)d_in[14];
  const float* b1_w2    = (const float*)d_in[15];
  const float* b1_b2    = (const float*)d_in[16];
  const float* b2_w1    = (const float*)d_in[17];
  const float* b2_b1    = (const float*)d_in[18];
  const float* b2_w2    = (const float*)d_in[19];
  const float* b2_b2    = (const float*)d_in[20];
  const float* nle_out_w= (const float*)d_in[21];
  const float* nle_out_b= (const float*)d_in[22];

  char* ws = (char*)d_ws;
  float*          xn   = (float*)(ws);                         // 0..4MB (reused: g12T)
  unsigned short* Qb   = (unsigned short*)(ws + (4u  << 20));  // 4..6
  unsigned short* Kb   = (unsigned short*)(ws + (6u  << 20));  // 6..8
  unsigned short* VTb  = (unsigned short*)(ws + (8u  << 20));  // 8..10
  unsigned short* OPb  = (unsigned short*)(ws + (10u << 20));  // 10..18 (4 x 2MB)
  float*          LSb  = (float*)(ws + (18u << 20));           // 18..18.25
  float*          xatt = (float*)(ws + (21u << 20));           // 21..25
  float*          t1   = (float*)(ws + (27u << 20));           // 27..35
  float*          t2   = (float*)(ws + (35u << 20));           // 35..43
  unsigned short* g12T = (unsigned short*)(ws);                // 0..4 (xn dead)

  k_ln_q        <<<256, 256, 0, stream>>>(x, cta_ln_g, cta_ln_b, q_w, q_b, xn, Qb);
  k_dwkv        <<<dim3(64, 8), 256, 0, stream>>>(xn, k_w, k_b, v_w, v_b, Kb, VTb);
  k_attn        <<<dim3(32, BATCH, NSPLIT), 256, 0, stream>>>(Qb, Kb, VTb, OPb, LSb);
  k_proj_ln2_pw <<<dim3(64, 4), 256, 0, stream>>>(OPb, LSb, x, cta_out_w, cta_out_b,
                                                  nle_ln_g, nle_ln_b,
                                                  b1_w1, b1_b1, b2_w1, b2_b1,
                                                  xatt, t1, t2);
  k_dwgelu      <<<dim3(64, 16), 256, 0, stream>>>(t1, t2, b1_w2, b1_b2, b2_w2, b2_b2, g12T);
  k_out         <<<dim3(64, 4), 256, 0, stream>>>(nle_out_w, nle_out_b, g12T, xatt, (float*)d_out);
}